// Round 1
// baseline (5445.541 us; speedup 1.0000x reference)
//
#include <hip/hip_runtime.h>

#define Bz 4
#define Cc 64
#define Tt 1000
#define Ff 129
#define TF 129000            // Tt*Ff
#define CTF 8256000          // Cc*TF
#define SZ 33024000L         // Bz*CTF
#define QKS 8256000L         // H*B*T*(E*F) = 16*1000*516
#define EPSv 1e-5f

// ---------------- reduction helpers ----------------
__device__ __forceinline__ float wave_sum(float v){
#pragma unroll
  for (int o = 32; o; o >>= 1) v += __shfl_down(v, o, 64);
  return v;
}
__device__ __forceinline__ float wave_bcast_sum(float v){
#pragma unroll
  for (int o = 1; o < 64; o <<= 1) v += __shfl_xor(v, o, 64);
  return v;
}
__device__ __forceinline__ float blk_sum256(float v, float* red){
  __syncthreads();
  v = wave_sum(v);
  int tid = threadIdx.x;
  if ((tid & 63) == 0) red[tid >> 6] = v;
  __syncthreads();
  return red[0] + red[1] + red[2] + red[3];
}
__device__ __forceinline__ float blk_max256(float v, float* red){
  __syncthreads();
#pragma unroll
  for (int o = 32; o; o >>= 1) v = fmaxf(v, __shfl_down(v, o, 64));
  int tid = threadIdx.x;
  if ((tid & 63) == 0) red[tid >> 6] = v;
  __syncthreads();
  return fmaxf(fmaxf(red[0], red[1]), fmaxf(red[2], red[3]));
}

// ---------------- misc ----------------
__global__ void k_zero(float* s){ if (threadIdx.x < 8) s[threadIdx.x] = 0.f; }

// ln4d: LN over channel axis per (b,t,f); std = sqrt(max(var, EPS))
__global__ void k_ln4d(const float* __restrict__ in, float* __restrict__ out,
                       const float* __restrict__ g, const float* __restrict__ be){
  int gid = blockIdx.x*256 + threadIdx.x;
  if (gid >= Bz*TF) return;
  int b = gid / TF, p = gid - b*TF;
  size_t base = (size_t)b*CTF + p;
  float v[64]; float s1 = 0.f, s2 = 0.f;
#pragma unroll
  for (int c = 0; c < 64; c++){ float x = in[base + (size_t)c*TF]; v[c] = x; s1 += x; s2 += x*x; }
  float mu = s1*(1.f/64.f);
  float var = s2*(1.f/64.f) - mu*mu;
  float rstd = rsqrtf(fmaxf(var, EPSv));
#pragma unroll
  for (int c = 0; c < 64; c++) out[base + (size_t)c*TF] = (v[c]-mu)*rstd*g[c] + be[c];
}

// per-(b,c) mean over (t,f) : contiguous TF floats
__global__ void k_chmean(const float* __restrict__ in, float* __restrict__ m){
  int bc = blockIdx.x;
  const float4* p = (const float4*)(in + (size_t)bc*TF);
  float s = 0.f;
  for (int i = threadIdx.x; i < TF/4; i += 256){ float4 u = p[i]; s += u.x+u.y+u.z+u.w; }
  __shared__ float red[4];
  s = blk_sum256(s, red);
  if (threadIdx.x == 0) m[bc] = s * (1.f/(float)TF);
}

// filt[b, gk] = tanh(sum_c m[b,c] * w[gk,c])
__global__ void k_filt(const float* __restrict__ m, const float* __restrict__ w, float* __restrict__ filt){
  int t = threadIdx.x;
  if (t >= Bz*12) return;
  int b = t/12, gk = t - b*12;
  float s = 0.f;
  for (int c = 0; c < 64; c++) s += m[b*64+c]*w[gk*64+c];
  filt[t] = tanhf(s);
}

// lisa horizontal: one wave per (b,c,t) row of 129
__global__ void k_lisa_h(const float* __restrict__ in, float* __restrict__ out,
                         const float* __restrict__ filt, const float* __restrict__ iap,
                         const float* __restrict__ llp, const float* __restrict__ lhp, int dil){
  __shared__ float r[132];
  int row = blockIdx.x;
  int c = (row / Tt) % Cc;
  int b = row / (Tt*Cc);
  size_t base = (size_t)row * Ff;
  int lane = threadIdx.x;
  float s = 0.f;
  for (int f = lane; f < Ff; f += 64){ float x = in[base+f]; r[f] = x; s += x; }
  s = wave_bcast_sum(s);
  float gap = s * (1.f/129.f);
  __syncthreads();
  int g3 = b*12 + (c>>4)*3;
  float w0 = filt[g3], w1 = filt[g3+1], w2 = filt[g3+2];
  float ia = iap[c], ll = llp[c], lh1 = lhp[c] + 1.f, ia1 = ia + 1.f;
  for (int f = lane; f < Ff; f += 64){
    int fm = f - dil; fm = fm < 0 ? -fm : fm;
    int fp = f + dil; fp = fp > 128 ? 256 - fp : fp;
    float conv = w0*r[fm] + w1*r[f] + w2*r[fp];
    out[base+f] = (conv*ia1 - ia*gap)*ll + r[f]*lh1;
  }
}

// column means over t per (b,c,f) for lisa vertical
__global__ void k_colmean(const float* __restrict__ in, float* __restrict__ gapv){
  int lane = threadIdx.x & 63, strip = threadIdx.x >> 6;
  int f = blockIdx.x*64 + lane;
  int c = blockIdx.y, b = blockIdx.z;
  size_t cb = ((size_t)(b*Cc + c))*TF + f;
  float s = 0.f;
  if (f < Ff){ for (int t = strip; t < Tt; t += 4) s += in[cb + (size_t)t*Ff]; }
  __shared__ float sm[256];
  sm[threadIdx.x] = s; __syncthreads();
  if (strip == 0 && f < Ff){
    float tot = sm[threadIdx.x] + sm[threadIdx.x+64] + sm[threadIdx.x+128] + sm[threadIdx.x+192];
    gapv[(b*Cc + c)*Ff + f] = tot * (1.f/(float)Tt);
  }
}

// lisa vertical fused with bsum accumulate: A (+)= mg*lisa(in) + mb*x
__global__ void k_lisa_v(const float* __restrict__ in, const float* __restrict__ x,
                         float* __restrict__ A, const float* __restrict__ filt,
                         const float* __restrict__ gapv,
                         const float* __restrict__ iap, const float* __restrict__ llp,
                         const float* __restrict__ lhp,
                         const float* __restrict__ mgp, const float* __restrict__ mbp,
                         int dil, int accum){
  int lane = threadIdx.x & 63, strip = threadIdx.x >> 6;
  int ftile = blockIdx.x % 3, tch = blockIdx.x / 3;   // 10 chunks of 100 t
  int f = ftile*64 + lane;
  if (f >= Ff) return;
  int c = blockIdx.y, b = blockIdx.z;
  int g3 = b*12 + (c>>4)*3;
  float w0 = filt[g3], w1 = filt[g3+1], w2 = filt[g3+2];
  float ia = iap[c], ll = llp[c], lh1 = lhp[c]+1.f, ia1 = ia+1.f;
  float mg = mgp[c], mb = mbp[c];
  float gap = gapv[(b*Cc+c)*Ff + f];
  size_t cb = ((size_t)(b*Cc + c))*TF + f;
  int tend = tch*100 + 100;
  for (int t = tch*100 + strip; t < tend; t += 4){
    int tm = t - dil; tm = tm < 0 ? -tm : tm;
    int tp = t + dil; tp = tp > 999 ? 1998 - tp : tp;
    float vm = in[cb + (size_t)tm*Ff];
    float vc = in[cb + (size_t)t*Ff];
    float vp = in[cb + (size_t)tp*Ff];
    float conv = w0*vm + w1*vc + w2*vp;
    float val = (conv*ia1 - ia*gap)*ll + vc*lh1;
    float o = mg*val + mb*x[cb + (size_t)t*Ff];
    size_t oi = cb + (size_t)t*Ff;
    A[oi] = accum ? (A[oi] + o) : o;
  }
}

// 1x1 conv 64->64: y[b,o,p] = sum_c A[b,c,p] W[o,c] + bias[o]
__global__ void k_convb(const float* __restrict__ in, float* __restrict__ out,
                        const float* __restrict__ W, const float* __restrict__ bias){
  __shared__ float Ws[4096];
  for (int i = threadIdx.x; i < 4096; i += 256) Ws[i] = W[i];
  __syncthreads();
  int gid = blockIdx.x*256 + threadIdx.x;
  if (gid >= Bz*TF) return;
  int b = gid / TF, p = gid - b*TF;
  size_t base = (size_t)b*CTF + p;
  float v[64];
#pragma unroll
  for (int c = 0; c < 64; c++) v[c] = in[base + (size_t)c*TF];
  for (int o = 0; o < 64; o++){
    float s = bias[o];
    const float4* w4 = (const float4*)&Ws[o*64];
#pragma unroll
    for (int c = 0; c < 16; c++){
      float4 w = w4[c];
      s += v[4*c]*w.x + v[4*c+1]*w.y + v[4*c+2]*w.z + v[4*c+3]*w.w;
    }
    out[base + (size_t)o*TF] = s;
  }
}

// per-batch global stats (sum, sumsq) via atomics
__global__ void k_gnstat(const float* __restrict__ y, float* __restrict__ stat){
  int b = blockIdx.y;
  const float4* p = (const float4*)(y + (size_t)b*CTF + (size_t)blockIdx.x*TF);
  float s1 = 0.f, s2 = 0.f;
  for (int i = threadIdx.x; i < TF/4; i += 256){
    float4 u = p[i];
    s1 += u.x+u.y+u.z+u.w;
    s2 += u.x*u.x+u.y*u.y+u.z*u.z+u.w*u.w;
  }
  __shared__ float red[4];
  s1 = blk_sum256(s1, red);
  s2 = blk_sum256(s2, red);
  if (threadIdx.x == 0){ atomicAdd(&stat[b*2], s1); atomicAdd(&stat[b*2+1], s2); }
}

// normalize + prelu (scalar alpha), in-place, float4
__global__ void k_gnapply(float* __restrict__ y, const float* __restrict__ g,
                          const float* __restrict__ be, const float* __restrict__ a,
                          const float* __restrict__ stat){
  size_t gid = (size_t)blockIdx.x*256 + threadIdx.x;
  if (gid >= (size_t)(SZ/4)) return;
  size_t e0 = gid*4;
  int b = (int)(e0 / CTF);
  int c = (int)((e0 / TF) & 63);
  float mu = stat[b*2] * (1.f/(float)CTF);
  float var = stat[b*2+1] * (1.f/(float)CTF) - mu*mu;
  float rstd = rsqrtf(var + EPSv);
  float gc = g[c], bc = be[c], al = a[0];
  float4 v = *(const float4*)(y + e0);
  float o[4] = {v.x, v.y, v.z, v.w};
#pragma unroll
  for (int i = 0; i < 4; i++){
    float z = (o[i]-mu)*rstd*gc + bc;
    o[i] = z >= 0.f ? z : al*z;
  }
  *(float4*)(y + e0) = make_float4(o[0], o[1], o[2], o[3]);
}

// one head-projection (R rows) + LN over (R,F), write contiguous R*F block
__device__ void qkv_one(const float (*yt)[130], float (*zt)[130], float* red,
                        const float* __restrict__ w, const float* __restrict__ bias,
                        float alpha, const float* __restrict__ lng, const float* __restrict__ lnb,
                        int R, float* __restrict__ outp){
  int tid = threadIdx.x;
  int n = R*Ff;
  int half = (R >> 1)*Ff;
  for (int idx = tid; idx < half; idx += 256){
    int e2 = idx / Ff, f = idx - e2*Ff;
    int e = e2*2;
    const float* wa = w + e*64; const float* wb = wa + 64;
    float sa = bias[e], sb = bias[e+1];
#pragma unroll 8
    for (int c = 0; c < 64; c++){ float yv = yt[c][f]; sa += yv*wa[c]; sb += yv*wb[c]; }
    sa = sa >= 0.f ? sa : alpha*sa;
    sb = sb >= 0.f ? sb : alpha*sb;
    zt[e][f] = sa; zt[e+1][f] = sb;
  }
  __syncthreads();
  float s1 = 0.f, s2 = 0.f;
  for (int idx = tid; idx < n; idx += 256){
    float v = zt[idx/Ff][idx % Ff]; s1 += v; s2 += v*v;
  }
  s1 = blk_sum256(s1, red);
  s2 = blk_sum256(s2, red);
  float mu = s1/(float)n;
  float rstd = rsqrtf(s2/(float)n - mu*mu + EPSv);
  for (int idx = tid; idx < n; idx += 256){
    float v = (zt[idx/Ff][idx % Ff] - mu)*rstd*lng[idx] + lnb[idx];
    outp[idx] = v;
  }
  __syncthreads();
}

__global__ void k_qkv(const float* __restrict__ Y,
                      const float* __restrict__ qw, const float* __restrict__ qb, const float* __restrict__ qa,
                      const float* __restrict__ qg, const float* __restrict__ qz,
                      const float* __restrict__ kw, const float* __restrict__ kb, const float* __restrict__ ka,
                      const float* __restrict__ kg, const float* __restrict__ kz,
                      const float* __restrict__ vw, const float* __restrict__ vb, const float* __restrict__ va,
                      const float* __restrict__ vg, const float* __restrict__ vz,
                      float* __restrict__ Qm, float* __restrict__ Km, float* __restrict__ Vm){
  __shared__ float yt[64][130];
  __shared__ float zt[16][130];
  __shared__ float red[4];
  int t = blockIdx.x, b = blockIdx.y;
  size_t base = (size_t)b*CTF + (size_t)t*Ff;
  for (int idx = threadIdx.x; idx < 64*Ff; idx += 256){
    int c = idx / Ff, f = idx - c*Ff;
    yt[c][f] = Y[base + (size_t)c*TF + f];
  }
  __syncthreads();
  for (int h = 0; h < 4; h++){
    size_t obase = (size_t)(h*Bz + b)*Tt + t;
    qkv_one(yt, zt, red, qw + h*4*64, qb + h*4, qa[h], qg + h*4*Ff, qz + h*4*Ff, 4, Qm + obase*516);
    qkv_one(yt, zt, red, kw + h*4*64, kb + h*4, ka[h], kg + h*4*Ff, kz + h*4*Ff, 4, Km + obase*516);
    qkv_one(yt, zt, red, vw + h*16*64, vb + h*16, va[h], vg + h*16*Ff, vz + h*16*Ff, 16, Vm + obase*2064);
  }
}

// S[hb][i][j] = dot(Q[hb,i,:516], K[hb,j,:516]) * 1/sqrt(516)
__global__ void k_scores(const float* __restrict__ Qm, const float* __restrict__ Km, float* __restrict__ S){
  __shared__ float Qs[16][65], Ks[16][65];
  int hb = blockIdx.y;
  int it = blockIdx.x >> 4, jt = blockIdx.x & 15;
  const float* Qb = Qm + (size_t)hb*Tt*516;
  const float* Kb = Km + (size_t)hb*Tt*516;
  float* Sb = S + (size_t)hb*Tt*Tt;
  int tid = threadIdx.x;
  int ti = tid >> 4, tj = tid & 15;
  int i0 = it*64, j0 = jt*64;
  float acc[4][4] = {};
  for (int kc = 0; kc < 516; kc += 16){
    for (int l = tid; l < 2048; l += 256){
      int sel = l >> 10;
      int ll = l & 1023;
      int r = ll >> 4, k = ll & 15;
      int kk = kc + k;
      if (sel == 0){
        int ri = i0 + r;
        Qs[k][r] = (ri < Tt && kk < 516) ? Qb[(size_t)ri*516 + kk] : 0.f;
      } else {
        int rj = j0 + r;
        Ks[k][r] = (rj < Tt && kk < 516) ? Kb[(size_t)rj*516 + kk] : 0.f;
      }
    }
    __syncthreads();
#pragma unroll
    for (int k = 0; k < 16; k++){
      float av[4], bv[4];
#pragma unroll
      for (int u = 0; u < 4; u++) av[u] = Qs[k][ti*4+u];
#pragma unroll
      for (int v = 0; v < 4; v++) bv[v] = Ks[k][tj*4+v];
#pragma unroll
      for (int u = 0; u < 4; u++)
#pragma unroll
        for (int v = 0; v < 4; v++) acc[u][v] += av[u]*bv[v];
    }
    __syncthreads();
  }
  const float sc = 0.04402254531f;   // 1/sqrt(516)
#pragma unroll
  for (int u = 0; u < 4; u++){
    int i = i0 + ti*4 + u;
    if (i >= Tt) continue;
#pragma unroll
    for (int v = 0; v < 4; v++){
      int j = j0 + tj*4 + v;
      if (j < Tt) Sb[(size_t)i*Tt + j] = acc[u][v]*sc;
    }
  }
}

__global__ void k_softmax(float* __restrict__ S){
  float* row = S + (size_t)blockIdx.x * Tt;
  int tid = threadIdx.x;
  __shared__ float red[4];
  float lv[4];
#pragma unroll
  for (int k = 0; k < 4; k++){ int idx = tid + k*256; lv[k] = (idx < Tt) ? row[idx] : -1e30f; }
  float m = fmaxf(fmaxf(lv[0], lv[1]), fmaxf(lv[2], lv[3]));
  m = blk_max256(m, red);
  float s = 0.f;
#pragma unroll
  for (int k = 0; k < 4; k++){ lv[k] = __expf(lv[k]-m); s += lv[k]; }
  s = blk_sum256(s, red);
  float inv = 1.f/s;
#pragma unroll
  for (int k = 0; k < 4; k++){ int idx = tid + k*256; if (idx < Tt) row[idx] = lv[k]*inv; }
}

// O = P @ V, written straight into (B, h*16+d, T, F) layout in d_out
__global__ void k_pv(const float* __restrict__ S, const float* __restrict__ Vm, float* __restrict__ Out){
  __shared__ float Ps[16][65], Vs[16][65];
  int jt = blockIdx.x, it = blockIdx.y, hb = blockIdx.z;
  int h = hb >> 2, b = hb & 3;
  const float* Pb = S + (size_t)hb*Tt*Tt;
  const float* Vb = Vm + (size_t)hb*Tt*2064;
  int tid = threadIdx.x, ti = tid >> 4, tj = tid & 15;
  int i0 = it*64, j0 = jt*64;
  float acc[4][4] = {};
  for (int kc = 0; kc < Tt; kc += 16){
    for (int l = tid; l < 1024; l += 256){
      int r = l >> 4, k = l & 15;
      int ri = i0 + r, kk = kc + k;
      Ps[k][r] = (ri < Tt && kk < Tt) ? Pb[(size_t)ri*Tt + kk] : 0.f;
    }
    for (int l = tid; l < 1024; l += 256){
      int k = l >> 6, j = l & 63;
      int kk = kc + k, jj = j0 + j;
      Vs[k][j] = (kk < Tt && jj < 2064) ? Vb[(size_t)kk*2064 + jj] : 0.f;
    }
    __syncthreads();
#pragma unroll
    for (int k = 0; k < 16; k++){
      float av[4], bv[4];
#pragma unroll
      for (int u = 0; u < 4; u++) av[u] = Ps[k][ti*4+u];
#pragma unroll
      for (int v = 0; v < 4; v++) bv[v] = Vs[k][tj*4+v];
#pragma unroll
      for (int u = 0; u < 4; u++)
#pragma unroll
        for (int v = 0; v < 4; v++) acc[u][v] += av[u]*bv[v];
    }
    __syncthreads();
  }
#pragma unroll
  for (int u = 0; u < 4; u++){
    int i = i0 + ti*4 + u;
    if (i >= Tt) continue;
#pragma unroll
    for (int v = 0; v < 4; v++){
      int j = j0 + tj*4 + v;
      if (j >= 2064) continue;
      int d = j / 129, f = j - d*129;
      Out[((size_t)(b*64 + h*16 + d)*Tt + i)*Ff + f] = acc[u][v];
    }
  }
}

// proj 1x1 conv + scalar prelu + LN over (C,F) per (b,t) + residual; in-place on d_out
__global__ void k_proj(float* __restrict__ Out, const float* __restrict__ Y,
                       const float* __restrict__ W, const float* __restrict__ bias,
                       const float* __restrict__ pa, const float* __restrict__ lng,
                       const float* __restrict__ lnb){
  __shared__ float ot[64][130];
  __shared__ float Ws[4096];
  __shared__ float red[4];
  int t = blockIdx.x, b = blockIdx.y;
  size_t base = (size_t)b*CTF + (size_t)t*Ff;
  for (int i = threadIdx.x; i < 4096; i += 256) Ws[i] = W[i];
  for (int idx = threadIdx.x; idx < 64*Ff; idx += 256){
    int c = idx / Ff, f = idx - c*Ff;
    ot[c][f] = Out[base + (size_t)c*TF + f];
  }
  __syncthreads();
  float alpha = pa[0];
  float pva[17], pvb[17];
  float s1 = 0.f, s2 = 0.f;
#pragma unroll
  for (int ki = 0; ki < 17; ki++){
    int idx = threadIdx.x + ki*256;
    if (idx < 32*Ff){
      int o2 = idx / Ff, f = idx - o2*Ff;
      int o = o2*2;
      const float* wa = &Ws[o*64]; const float* wb = wa + 64;
      float sa = bias[o], sb = bias[o+1];
#pragma unroll 8
      for (int c = 0; c < 64; c++){ float v = ot[c][f]; sa += v*wa[c]; sb += v*wb[c]; }
      sa = sa >= 0.f ? sa : alpha*sa;
      sb = sb >= 0.f ? sb : alpha*sb;
      pva[ki] = sa; pvb[ki] = sb;
      s1 += sa + sb; s2 += sa*sa + sb*sb;
    }
  }
  s1 = blk_sum256(s1, red);
  s2 = blk_sum256(s2, red);
  const float n = 64.f*129.f;
  float mu = s1/n;
  float rstd = rsqrtf(s2/n - mu*mu + EPSv);
#pragma unroll
  for (int ki = 0; ki < 17; ki++){
    int idx = threadIdx.x + ki*256;
    if (idx < 32*Ff){
      int o2 = idx / Ff, f = idx - o2*Ff;
      int o = o2*2;
      float va = (pva[ki]-mu)*rstd*lng[o*Ff+f] + lnb[o*Ff+f];
      float vb = (pvb[ki]-mu)*rstd*lng[(o+1)*Ff+f] + lnb[(o+1)*Ff+f];
      Out[base + (size_t)o*TF + f]     = va + Y[base + (size_t)o*TF + f];
      Out[base + (size_t)(o+1)*TF + f] = vb + Y[base + (size_t)(o+1)*TF + f];
    }
  }
}

extern "C" void kernel_launch(void* const* d_in, const int* in_sizes, int n_in,
                              void* d_out, int out_size, void* d_ws, size_t ws_size,
                              hipStream_t stream){
  const float* x       = (const float*)d_in[0];
  const float* br_g    = (const float*)d_in[1];
  const float* br_b    = (const float*)d_in[2];
  const float* lisa_w  = (const float*)d_in[3];
  const float* lisa_in = (const float*)d_in[4];
  const float* lisa_ll = (const float*)d_in[5];
  const float* lisa_lh = (const float*)d_in[6];
  const float* mix_g   = (const float*)d_in[7];
  const float* mix_b   = (const float*)d_in[8];
  const float* convb_w = (const float*)d_in[9];
  const float* convb_b = (const float*)d_in[10];
  const float* gn_g    = (const float*)d_in[11];
  const float* gn_b    = (const float*)d_in[12];
  const float* convb_a = (const float*)d_in[13];
  const float* q_w  = (const float*)d_in[14];
  const float* q_b  = (const float*)d_in[15];
  const float* q_a  = (const float*)d_in[16];
  const float* q_lg = (const float*)d_in[17];
  const float* q_lb = (const float*)d_in[18];
  const float* k_w  = (const float*)d_in[19];
  const float* k_b  = (const float*)d_in[20];
  const float* k_a  = (const float*)d_in[21];
  const float* k_lg = (const float*)d_in[22];
  const float* k_lb = (const float*)d_in[23];
  const float* v_w  = (const float*)d_in[24];
  const float* v_b  = (const float*)d_in[25];
  const float* v_a  = (const float*)d_in[26];
  const float* v_lg = (const float*)d_in[27];
  const float* v_lb = (const float*)d_in[28];
  const float* p_w  = (const float*)d_in[29];
  const float* p_b  = (const float*)d_in[30];
  const float* p_a  = (const float*)d_in[31];
  const float* p_lg = (const float*)d_in[32];
  const float* p_lb = (const float*)d_in[33];

  float* out  = (float*)d_out;
  float* buf0 = (float*)d_ws;          // A (bsum) -> later Vm
  float* buf1 = buf0 + SZ;             // ln temp -> Y ("output")
  float* buf2 = buf1 + SZ;             // lisa_h temp -> Qm|Km|S
  float* chm  = buf2 + SZ;             // 256
  float* filt = chm + 256;             // 48 (pad to 64)
  float* stat = filt + 64;             // 8  (pad to 16)
  float* gapv = stat + 16;             // 33024

  if (ws_size < (3*(size_t)SZ + 40000)*sizeof(float)) return;  // need ~396.5 MB

  float* Qm = buf2;
  float* Km = buf2 + QKS;
  float* Sb = buf2 + 2*QKS;  // 16e6 floats, fits remaining 16.512e6
  float* Vm = buf0;

  k_zero<<<1, 64, 0, stream>>>(stat);

  const int dils[3] = {3, 5, 7};
  for (int i = 0; i < 3; i++){
    k_ln4d<<<2016, 256, 0, stream>>>(x, buf1, br_g + i*64, br_b + i*64);
    k_chmean<<<256, 256, 0, stream>>>(buf1, chm);
    k_filt<<<1, 64, 0, stream>>>(chm, lisa_w + i*768, filt);
    k_lisa_h<<<Bz*Cc*Tt, 64, 0, stream>>>(buf1, buf2, filt, lisa_in + i*64, lisa_ll + i*64, lisa_lh + i*64, dils[i]);
    k_ln4d<<<2016, 256, 0, stream>>>(buf2, buf1, br_g + (i+3)*64, br_b + (i+3)*64);
    k_chmean<<<256, 256, 0, stream>>>(buf1, chm);
    k_filt<<<1, 64, 0, stream>>>(chm, lisa_w + (i+3)*768, filt);
    k_colmean<<<dim3(3, 64, 4), 256, 0, stream>>>(buf1, gapv);
    k_lisa_v<<<dim3(30, 64, 4), 256, 0, stream>>>(buf1, x, buf0, filt, gapv,
        lisa_in + (i+3)*64, lisa_ll + (i+3)*64, lisa_lh + (i+3)*64,
        mix_g + i*64, mix_b + i*64, dils[i], i > 0 ? 1 : 0);
  }
  k_convb<<<2016, 256, 0, stream>>>(buf0, buf1, convb_w, convb_b);
  k_gnstat<<<dim3(64, 4), 256, 0, stream>>>(buf1, stat);
  k_gnapply<<<32250, 256, 0, stream>>>(buf1, gn_g, gn_b, convb_a, stat);
  k_qkv<<<dim3(1000, 4), 256, 0, stream>>>(buf1,
      q_w, q_b, q_a, q_lg, q_lb,
      k_w, k_b, k_a, k_lg, k_lb,
      v_w, v_b, v_a, v_lg, v_lb,
      Qm, Km, Vm);
  k_scores<<<dim3(256, 16), 256, 0, stream>>>(Qm, Km, Sb);
  k_softmax<<<16000, 256, 0, stream>>>(Sb);
  k_pv<<<dim3(33, 16, 16), 256, 0, stream>>>(Sb, Vm, out);
  k_proj<<<dim3(1000, 4), 256, 0, stream>>>(out, buf1, p_w, p_b, p_a, p_lg, p_lb);
}

// Round 2
// 3709.631 us; speedup vs baseline: 1.4679x; 1.4679x over previous
//
#include <hip/hip_runtime.h>
#include <hip/hip_bf16.h>

#define Bz 4
#define Cc 64
#define Tt 1000
#define Ff 129
#define TF 129000            // Tt*Ff
#define CTF 8256000          // Cc*TF
#define SZ 33024000L         // Bz*CTF
#define EPSv 1e-5f

#define KQK 544              // 516 padded to mult of 32
#define KPV 1024             // 1000 padded
#define LDP 2000             // P row stride in bf16 (= 1000 f32 reused in place)
#define NV 2064              // 16*129

typedef __attribute__((ext_vector_type(8))) short bf16x8;
typedef __attribute__((ext_vector_type(4))) float f32x4;

// ---------------- reduction helpers ----------------
__device__ __forceinline__ float wave_sum(float v){
#pragma unroll
  for (int o = 32; o; o >>= 1) v += __shfl_down(v, o, 64);
  return v;
}
__device__ __forceinline__ float wave_bcast_sum(float v){
#pragma unroll
  for (int o = 1; o < 64; o <<= 1) v += __shfl_xor(v, o, 64);
  return v;
}
__device__ __forceinline__ float blk_sum256(float v, float* red){
  __syncthreads();
  v = wave_sum(v);
  int tid = threadIdx.x;
  if ((tid & 63) == 0) red[tid >> 6] = v;
  __syncthreads();
  return red[0] + red[1] + red[2] + red[3];
}
__device__ __forceinline__ float blk_max256(float v, float* red){
  __syncthreads();
#pragma unroll
  for (int o = 32; o; o >>= 1) v = fmaxf(v, __shfl_down(v, o, 64));
  int tid = threadIdx.x;
  if ((tid & 63) == 0) red[tid >> 6] = v;
  __syncthreads();
  return fmaxf(fmaxf(red[0], red[1]), fmaxf(red[2], red[3]));
}

// ---------------- misc ----------------
__global__ void k_zero(float* s){ if (threadIdx.x < 8) s[threadIdx.x] = 0.f; }

// ln4d: LN over channel axis per (b,t,f); std = sqrt(max(var, EPS))
__global__ void k_ln4d(const float* __restrict__ in, float* __restrict__ out,
                       const float* __restrict__ g, const float* __restrict__ be){
  int gid = blockIdx.x*256 + threadIdx.x;
  if (gid >= Bz*TF) return;
  int b = gid / TF, p = gid - b*TF;
  size_t base = (size_t)b*CTF + p;
  float v[64]; float s1 = 0.f, s2 = 0.f;
#pragma unroll
  for (int c = 0; c < 64; c++){ float x = in[base + (size_t)c*TF]; v[c] = x; s1 += x; s2 += x*x; }
  float mu = s1*(1.f/64.f);
  float var = s2*(1.f/64.f) - mu*mu;
  float rstd = rsqrtf(fmaxf(var, EPSv));
#pragma unroll
  for (int c = 0; c < 64; c++) out[base + (size_t)c*TF] = (v[c]-mu)*rstd*g[c] + be[c];
}

// per-(b,c) mean over (t,f)
__global__ void k_chmean(const float* __restrict__ in, float* __restrict__ m){
  int bc = blockIdx.x;
  const float4* p = (const float4*)(in + (size_t)bc*TF);
  float s = 0.f;
  for (int i = threadIdx.x; i < TF/4; i += 256){ float4 u = p[i]; s += u.x+u.y+u.z+u.w; }
  __shared__ float red[4];
  s = blk_sum256(s, red);
  if (threadIdx.x == 0) m[bc] = s * (1.f/(float)TF);
}

__global__ void k_filt(const float* __restrict__ m, const float* __restrict__ w, float* __restrict__ filt){
  int t = threadIdx.x;
  if (t >= Bz*12) return;
  int b = t/12, gk = t - b*12;
  float s = 0.f;
  for (int c = 0; c < 64; c++) s += m[b*64+c]*w[gk*64+c];
  filt[t] = tanhf(s);
}

// lisa horizontal: one wave per (b,c,t) row of 129
__global__ void k_lisa_h(const float* __restrict__ in, float* __restrict__ out,
                         const float* __restrict__ filt, const float* __restrict__ iap,
                         const float* __restrict__ llp, const float* __restrict__ lhp, int dil){
  __shared__ float r[132];
  int row = blockIdx.x;
  int c = (row / Tt) % Cc;
  int b = row / (Tt*Cc);
  size_t base = (size_t)row * Ff;
  int lane = threadIdx.x;
  float s = 0.f;
  for (int f = lane; f < Ff; f += 64){ float x = in[base+f]; r[f] = x; s += x; }
  s = wave_bcast_sum(s);
  float gap = s * (1.f/129.f);
  __syncthreads();
  int g3 = b*12 + (c>>4)*3;
  float w0 = filt[g3], w1 = filt[g3+1], w2 = filt[g3+2];
  float ia = iap[c], ll = llp[c], lh1 = lhp[c] + 1.f, ia1 = ia + 1.f;
  for (int f = lane; f < Ff; f += 64){
    int fm = f - dil; fm = fm < 0 ? -fm : fm;
    int fp = f + dil; fp = fp > 128 ? 256 - fp : fp;
    float conv = w0*r[fm] + w1*r[f] + w2*r[fp];
    out[base+f] = (conv*ia1 - ia*gap)*ll + r[f]*lh1;
  }
}

// column means over t per (b,c,f)
__global__ void k_colmean(const float* __restrict__ in, float* __restrict__ gapv){
  int lane = threadIdx.x & 63, strip = threadIdx.x >> 6;
  int f = blockIdx.x*64 + lane;
  int c = blockIdx.y, b = blockIdx.z;
  size_t cb = ((size_t)(b*Cc + c))*TF + f;
  float s = 0.f;
  if (f < Ff){ for (int t = strip; t < Tt; t += 4) s += in[cb + (size_t)t*Ff]; }
  __shared__ float sm[256];
  sm[threadIdx.x] = s; __syncthreads();
  if (strip == 0 && f < Ff){
    float tot = sm[threadIdx.x] + sm[threadIdx.x+64] + sm[threadIdx.x+128] + sm[threadIdx.x+192];
    gapv[(b*Cc + c)*Ff + f] = tot * (1.f/(float)Tt);
  }
}

// lisa vertical fused with bsum accumulate
__global__ void k_lisa_v(const float* __restrict__ in, const float* __restrict__ x,
                         float* __restrict__ A, const float* __restrict__ filt,
                         const float* __restrict__ gapv,
                         const float* __restrict__ iap, const float* __restrict__ llp,
                         const float* __restrict__ lhp,
                         const float* __restrict__ mgp, const float* __restrict__ mbp,
                         int dil, int accum){
  int lane = threadIdx.x & 63, strip = threadIdx.x >> 6;
  int ftile = blockIdx.x % 3, tch = blockIdx.x / 3;
  int f = ftile*64 + lane;
  if (f >= Ff) return;
  int c = blockIdx.y, b = blockIdx.z;
  int g3 = b*12 + (c>>4)*3;
  float w0 = filt[g3], w1 = filt[g3+1], w2 = filt[g3+2];
  float ia = iap[c], ll = llp[c], lh1 = lhp[c]+1.f, ia1 = ia+1.f;
  float mg = mgp[c], mb = mbp[c];
  float gap = gapv[(b*Cc+c)*Ff + f];
  size_t cb = ((size_t)(b*Cc + c))*TF + f;
  int tend = tch*100 + 100;
  for (int t = tch*100 + strip; t < tend; t += 4){
    int tm = t - dil; tm = tm < 0 ? -tm : tm;
    int tp = t + dil; tp = tp > 999 ? 1998 - tp : tp;
    float vm = in[cb + (size_t)tm*Ff];
    float vc = in[cb + (size_t)t*Ff];
    float vp = in[cb + (size_t)tp*Ff];
    float conv = w0*vm + w1*vc + w2*vp;
    float val = (conv*ia1 - ia*gap)*ll + vc*lh1;
    float o = mg*val + mb*x[cb + (size_t)t*Ff];
    size_t oi = cb + (size_t)t*Ff;
    A[oi] = accum ? (A[oi] + o) : o;
  }
}

// 1x1 conv 64->64
__global__ void k_convb(const float* __restrict__ in, float* __restrict__ out,
                        const float* __restrict__ W, const float* __restrict__ bias){
  __shared__ float Ws[4096];
  for (int i = threadIdx.x; i < 4096; i += 256) Ws[i] = W[i];
  __syncthreads();
  int gid = blockIdx.x*256 + threadIdx.x;
  if (gid >= Bz*TF) return;
  int b = gid / TF, p = gid - b*TF;
  size_t base = (size_t)b*CTF + p;
  float v[64];
#pragma unroll
  for (int c = 0; c < 64; c++) v[c] = in[base + (size_t)c*TF];
  for (int o = 0; o < 64; o++){
    float s = bias[o];
    const float4* w4 = (const float4*)&Ws[o*64];
#pragma unroll
    for (int c = 0; c < 16; c++){
      float4 w = w4[c];
      s += v[4*c]*w.x + v[4*c+1]*w.y + v[4*c+2]*w.z + v[4*c+3]*w.w;
    }
    out[base + (size_t)o*TF] = s;
  }
}

// per-batch global stats
__global__ void k_gnstat(const float* __restrict__ y, float* __restrict__ stat){
  int b = blockIdx.y;
  const float4* p = (const float4*)(y + (size_t)b*CTF + (size_t)blockIdx.x*TF);
  float s1 = 0.f, s2 = 0.f;
  for (int i = threadIdx.x; i < TF/4; i += 256){
    float4 u = p[i];
    s1 += u.x+u.y+u.z+u.w;
    s2 += u.x*u.x+u.y*u.y+u.z*u.z+u.w*u.w;
  }
  __shared__ float red[4];
  s1 = blk_sum256(s1, red);
  s2 = blk_sum256(s2, red);
  if (threadIdx.x == 0){ atomicAdd(&stat[b*2], s1); atomicAdd(&stat[b*2+1], s2); }
}

__global__ void k_gnapply(float* __restrict__ y, const float* __restrict__ g,
                          const float* __restrict__ be, const float* __restrict__ a,
                          const float* __restrict__ stat){
  size_t gid = (size_t)blockIdx.x*256 + threadIdx.x;
  if (gid >= (size_t)(SZ/4)) return;
  size_t e0 = gid*4;
  int b = (int)(e0 / CTF);
  int c = (int)((e0 / TF) & 63);
  float mu = stat[b*2] * (1.f/(float)CTF);
  float var = stat[b*2+1] * (1.f/(float)CTF) - mu*mu;
  float rstd = rsqrtf(var + EPSv);
  float gc = g[c], bc = be[c], al = a[0];
  float4 v = *(const float4*)(y + e0);
  float o[4] = {v.x, v.y, v.z, v.w};
#pragma unroll
  for (int i = 0; i < 4; i++){
    float z = (o[i]-mu)*rstd*gc + bc;
    o[i] = z >= 0.f ? z : al*z;
  }
  *(float4*)(y + e0) = make_float4(o[0], o[1], o[2], o[3]);
}

// one head-projection + LN over (R,F); writes bf16 row of length npad (zero pad)
__device__ void qkv_one(const float (*yt)[130], float (*zt)[130], float* red,
                        const float* __restrict__ w, const float* __restrict__ bias,
                        float alpha, const float* __restrict__ lng, const float* __restrict__ lnb,
                        int R, int npad, __hip_bfloat16* __restrict__ outp){
  int tid = threadIdx.x;
  int n = R*Ff;
  int half = (R >> 1)*Ff;
  for (int idx = tid; idx < half; idx += 256){
    int e2 = idx / Ff, f = idx - e2*Ff;
    int e = e2*2;
    const float* wa = w + e*64; const float* wb = wa + 64;
    float sa = bias[e], sb = bias[e+1];
#pragma unroll 8
    for (int c = 0; c < 64; c++){ float yv = yt[c][f]; sa += yv*wa[c]; sb += yv*wb[c]; }
    sa = sa >= 0.f ? sa : alpha*sa;
    sb = sb >= 0.f ? sb : alpha*sb;
    zt[e][f] = sa; zt[e+1][f] = sb;
  }
  __syncthreads();
  float s1 = 0.f, s2 = 0.f;
  for (int idx = tid; idx < n; idx += 256){
    float v = zt[idx/Ff][idx % Ff]; s1 += v; s2 += v*v;
  }
  s1 = blk_sum256(s1, red);
  s2 = blk_sum256(s2, red);
  float mu = s1/(float)n;
  float rstd = rsqrtf(s2/(float)n - mu*mu + EPSv);
  for (int idx = tid; idx < npad; idx += 256){
    float v = 0.f;
    if (idx < n) v = (zt[idx/Ff][idx % Ff] - mu)*rstd*lng[idx] + lnb[idx];
    outp[idx] = __float2bfloat16(v);
  }
  __syncthreads();
}

__global__ void k_qkv(const float* __restrict__ Y,
                      const float* __restrict__ qw, const float* __restrict__ qb, const float* __restrict__ qa,
                      const float* __restrict__ qg, const float* __restrict__ qz,
                      const float* __restrict__ kw, const float* __restrict__ kb, const float* __restrict__ ka,
                      const float* __restrict__ kg, const float* __restrict__ kz,
                      const float* __restrict__ vw, const float* __restrict__ vb, const float* __restrict__ va,
                      const float* __restrict__ vg, const float* __restrict__ vz,
                      __hip_bfloat16* __restrict__ Qm, __hip_bfloat16* __restrict__ Km,
                      __hip_bfloat16* __restrict__ Vm){
  __shared__ float yt[64][130];
  __shared__ float zt[16][130];
  __shared__ float red[4];
  int t = blockIdx.x, b = blockIdx.y;
  size_t base = (size_t)b*CTF + (size_t)t*Ff;
  for (int idx = threadIdx.x; idx < 64*Ff; idx += 256){
    int c = idx / Ff, f = idx - c*Ff;
    yt[c][f] = Y[base + (size_t)c*TF + f];
  }
  __syncthreads();
  for (int h = 0; h < 4; h++){
    size_t obase = (size_t)(h*Bz + b)*Tt + t;
    qkv_one(yt, zt, red, qw + h*4*64, qb + h*4, qa[h], qg + h*4*Ff, qz + h*4*Ff, 4, KQK, Qm + obase*KQK);
    qkv_one(yt, zt, red, kw + h*4*64, kb + h*4, ka[h], kg + h*4*Ff, kz + h*4*Ff, 4, KQK, Km + obase*KQK);
    qkv_one(yt, zt, red, vw + h*16*64, vb + h*16, va[h], vg + h*16*Ff, vz + h*16*Ff, 16, NV, Vm + obase*NV);
  }
}

// transpose V: Vm[hb][t][n] -> Vt[hb][n][tp] with tp-stride KPV, zero pad t>=1000
__global__ void k_vt(const ushort* __restrict__ Vm, ushort* __restrict__ Vt){
  __shared__ ushort tile[64][72];
  int t0 = blockIdx.x*64, n0 = blockIdx.y*64, hb = blockIdx.z;
  const ushort* src = Vm + (size_t)hb*Tt*NV;
  ushort* dst = Vt + (size_t)hb*NV*KPV;
  int nl = threadIdx.x & 63, tl = threadIdx.x >> 6;
#pragma unroll
  for (int i = 0; i < 16; i++){
    int t = tl + i*4;
    int gt = t0 + t, gn = n0 + nl;
    ushort v = 0;
    if (gt < Tt && gn < NV) v = src[(size_t)gt*NV + gn];
    tile[t][nl] = v;
  }
  __syncthreads();
  int tl2 = threadIdx.x & 63, nl2 = threadIdx.x >> 6;
#pragma unroll
  for (int i = 0; i < 16; i++){
    int n = nl2 + i*4;
    int gn = n0 + n;
    if (gn < NV) dst[(size_t)gn*KPV + t0 + tl2] = tile[tl2][n];
  }
}

// ---------------- bf16 MFMA GEMM: C[M,N] = A[M,Kc] * B^T[N,Kc]  ----------------
// MODE 0: scores -> C = S + hb*strideC, ldc=1000, scale alpha
// MODE 1: PV     -> scatter into d_out (B,64,T,F) layout
template<int MODE>
__global__ __launch_bounds__(256) void k_gemm(
    const ushort* __restrict__ A, int lda, long strideA,
    const ushort* __restrict__ Bt, int ldb, long strideB,
    float* __restrict__ C, long strideC,
    int M, int N, int Kc, float alpha){
  __shared__ ushort As[128*40];
  __shared__ ushort Bs[128*40];
  int hb = blockIdx.z;
  const ushort* Ab = A + (long)hb*strideA;
  const ushort* Bb = Bt + (long)hb*strideB;
  int i0 = blockIdx.y*128, j0 = blockIdx.x*128;
  int tid = threadIdx.x;
  int wave = tid >> 6, lane = tid & 63;
  int wm = (wave >> 1)*64, wn = (wave & 1)*64;
  int col16 = lane & 15, quad = lane >> 4;
  f32x4 acc[4][4] = {};
  int srow = tid >> 2;
  int scol = (tid & 3)*8;
  for (int k0 = 0; k0 < Kc; k0 += 32){
#pragma unroll
    for (int r = 0; r < 2; r++){
      int row = srow + r*64;
      int gi = i0 + row;
      float4 va = (gi < M) ? *(const float4*)(Ab + (long)gi*lda + k0 + scol)
                           : make_float4(0.f,0.f,0.f,0.f);
      *(float4*)&As[row*40 + scol] = va;
      int gj = j0 + row;
      float4 vb = (gj < N) ? *(const float4*)(Bb + (long)gj*ldb + k0 + scol)
                           : make_float4(0.f,0.f,0.f,0.f);
      *(float4*)&Bs[row*40 + scol] = vb;
    }
    __syncthreads();
    bf16x8 af[4], bfr[4];
#pragma unroll
    for (int mt = 0; mt < 4; mt++) af[mt]  = *(const bf16x8*)&As[(wm + mt*16 + col16)*40 + quad*8];
#pragma unroll
    for (int nt = 0; nt < 4; nt++) bfr[nt] = *(const bf16x8*)&Bs[(wn + nt*16 + col16)*40 + quad*8];
#pragma unroll
    for (int mt = 0; mt < 4; mt++)
#pragma unroll
      for (int nt = 0; nt < 4; nt++)
        acc[mt][nt] = __builtin_amdgcn_mfma_f32_16x16x32_bf16(af[mt], bfr[nt], acc[mt][nt], 0, 0, 0);
    __syncthreads();
  }
  // epilogue: D element (row = quad*4+rg, col = lane&15) per 16x16 tile
  if (MODE == 0){
    float* Cb = C + (long)hb*strideC;
#pragma unroll
    for (int mt = 0; mt < 4; mt++){
      int ibase = i0 + wm + mt*16 + quad*4;
#pragma unroll
      for (int nt = 0; nt < 4; nt++){
        int j = j0 + wn + nt*16 + col16;
        if (j < N){
#pragma unroll
          for (int rg = 0; rg < 4; rg++){
            int i = ibase + rg;
            if (i < M) Cb[(long)i*N + j] = acc[mt][nt][rg]*alpha;
          }
        }
      }
    }
  } else {
    int h = hb >> 2, b = hb & 3;
#pragma unroll
    for (int mt = 0; mt < 4; mt++){
      int ibase = i0 + wm + mt*16 + quad*4;
#pragma unroll
      for (int nt = 0; nt < 4; nt++){
        int n = j0 + wn + nt*16 + col16;
        if (n < NV){
          int d = n / 129, f = n - d*129;
          float* oc = C + ((long)(b*64 + h*16 + d)*Tt)*Ff + f;
#pragma unroll
          for (int rg = 0; rg < 4; rg++){
            int i = ibase + rg;
            if (i < M) oc[(long)i*Ff] = acc[mt][nt][rg];
          }
        }
      }
    }
  }
}

// softmax over row of 1000 f32; writes P bf16 (padded to 1024, zeros) in place into row
__global__ void k_softmax(float* __restrict__ S){
  float* row = S + (size_t)blockIdx.x * Tt;
  __hip_bfloat16* prow = (__hip_bfloat16*)row;  // bf16 row, stride LDP, fits in 4000B
  int tid = threadIdx.x;
  __shared__ float red[4];
  float lv[4];
#pragma unroll
  for (int k = 0; k < 4; k++){ int idx = tid + k*256; lv[k] = (idx < Tt) ? row[idx] : -1e30f; }
  float m = fmaxf(fmaxf(lv[0], lv[1]), fmaxf(lv[2], lv[3]));
  m = blk_max256(m, red);
  float s = 0.f;
#pragma unroll
  for (int k = 0; k < 4; k++){ lv[k] = __expf(lv[k]-m); s += lv[k]; }
  s = blk_sum256(s, red);
  float inv = 1.f/s;
#pragma unroll
  for (int k = 0; k < 4; k++){
    int idx = tid + k*256;   // 0..1023
    prow[idx] = __float2bfloat16(idx < Tt ? lv[k]*inv : 0.f);
  }
}

// proj 1x1 conv + scalar prelu + LN over (C,F) per (b,t) + residual; in-place on d_out
__global__ void k_proj(float* __restrict__ Out, const float* __restrict__ Y,
                       const float* __restrict__ W, const float* __restrict__ bias,
                       const float* __restrict__ pa, const float* __restrict__ lng,
                       const float* __restrict__ lnb){
  __shared__ float ot[64][130];
  __shared__ float Ws[4096];
  __shared__ float red[4];
  int t = blockIdx.x, b = blockIdx.y;
  size_t base = (size_t)b*CTF + (size_t)t*Ff;
  for (int i = threadIdx.x; i < 4096; i += 256) Ws[i] = W[i];
  for (int idx = threadIdx.x; idx < 64*Ff; idx += 256){
    int c = idx / Ff, f = idx - c*Ff;
    ot[c][f] = Out[base + (size_t)c*TF + f];
  }
  __syncthreads();
  float alpha = pa[0];
  float pva[17], pvb[17];
  float s1 = 0.f, s2 = 0.f;
#pragma unroll
  for (int ki = 0; ki < 17; ki++){
    int idx = threadIdx.x + ki*256;
    if (idx < 32*Ff){
      int o2 = idx / Ff, f = idx - o2*Ff;
      int o = o2*2;
      const float* wa = &Ws[o*64]; const float* wb = wa + 64;
      float sa = bias[o], sb = bias[o+1];
#pragma unroll 8
      for (int c = 0; c < 64; c++){ float v = ot[c][f]; sa += v*wa[c]; sb += v*wb[c]; }
      sa = sa >= 0.f ? sa : alpha*sa;
      sb = sb >= 0.f ? sb : alpha*sb;
      pva[ki] = sa; pvb[ki] = sb;
      s1 += sa + sb; s2 += sa*sa + sb*sb;
    }
  }
  s1 = blk_sum256(s1, red);
  s2 = blk_sum256(s2, red);
  const float n = 64.f*129.f;
  float mu = s1/n;
  float rstd = rsqrtf(s2/n - mu*mu + EPSv);
#pragma unroll
  for (int ki = 0; ki < 17; ki++){
    int idx = threadIdx.x + ki*256;
    if (idx < 32*Ff){
      int o2 = idx / Ff, f = idx - o2*Ff;
      int o = o2*2;
      float va = (pva[ki]-mu)*rstd*lng[o*Ff+f] + lnb[o*Ff+f];
      float vb = (pvb[ki]-mu)*rstd*lng[(o+1)*Ff+f] + lnb[(o+1)*Ff+f];
      Out[base + (size_t)o*TF + f]     = va + Y[base + (size_t)o*TF + f];
      Out[base + (size_t)(o+1)*TF + f] = vb + Y[base + (size_t)(o+1)*TF + f];
    }
  }
}

extern "C" void kernel_launch(void* const* d_in, const int* in_sizes, int n_in,
                              void* d_out, int out_size, void* d_ws, size_t ws_size,
                              hipStream_t stream){
  const float* x       = (const float*)d_in[0];
  const float* br_g    = (const float*)d_in[1];
  const float* br_b    = (const float*)d_in[2];
  const float* lisa_w  = (const float*)d_in[3];
  const float* lisa_in = (const float*)d_in[4];
  const float* lisa_ll = (const float*)d_in[5];
  const float* lisa_lh = (const float*)d_in[6];
  const float* mix_g   = (const float*)d_in[7];
  const float* mix_b   = (const float*)d_in[8];
  const float* convb_w = (const float*)d_in[9];
  const float* convb_b = (const float*)d_in[10];
  const float* gn_g    = (const float*)d_in[11];
  const float* gn_b    = (const float*)d_in[12];
  const float* convb_a = (const float*)d_in[13];
  const float* q_w  = (const float*)d_in[14];
  const float* q_b  = (const float*)d_in[15];
  const float* q_a  = (const float*)d_in[16];
  const float* q_lg = (const float*)d_in[17];
  const float* q_lb = (const float*)d_in[18];
  const float* k_w  = (const float*)d_in[19];
  const float* k_b  = (const float*)d_in[20];
  const float* k_a  = (const float*)d_in[21];
  const float* k_lg = (const float*)d_in[22];
  const float* k_lb = (const float*)d_in[23];
  const float* v_w  = (const float*)d_in[24];
  const float* v_b  = (const float*)d_in[25];
  const float* v_a  = (const float*)d_in[26];
  const float* v_lg = (const float*)d_in[27];
  const float* v_lb = (const float*)d_in[28];
  const float* p_w  = (const float*)d_in[29];
  const float* p_b  = (const float*)d_in[30];
  const float* p_a  = (const float*)d_in[31];
  const float* p_lg = (const float*)d_in[32];
  const float* p_lb = (const float*)d_in[33];

  float* out  = (float*)d_out;
  float* buf0 = (float*)d_ws;          // bsum -> later Vt|S
  float* buf1 = buf0 + SZ;             // ln temp -> Y ("output")
  float* buf2 = buf1 + SZ;             // lisa_h temp -> Qm|Km|Vm (bf16)
  float* chm  = buf2 + SZ;             // 256
  float* filt = chm + 256;             // 48 (pad 64)
  float* stat = filt + 64;             // 8  (pad 16)
  float* gapv = stat + 16;             // 33024

  if (ws_size < (3*(size_t)SZ + 40000)*sizeof(float)) return;

  // attention buffers (bf16 views)
  __hip_bfloat16* Qm = (__hip_bfloat16*)buf2;                 // 16*1000*544
  __hip_bfloat16* Km = Qm + (size_t)16*Tt*KQK;                // 16*1000*544
  __hip_bfloat16* Vm = Km + (size_t)16*Tt*KQK;                // 16*1000*2064
  ushort* Vt = (ushort*)buf0;                                 // 16*2064*1024 bf16
  float*  S  = buf0 + (size_t)16*NV*KPV/2;                    // 16*1000*1000 f32 (P bf16 in place)

  k_zero<<<1, 64, 0, stream>>>(stat);

  const int dils[3] = {3, 5, 7};
  for (int i = 0; i < 3; i++){
    k_ln4d<<<2016, 256, 0, stream>>>(x, buf1, br_g + i*64, br_b + i*64);
    k_chmean<<<256, 256, 0, stream>>>(buf1, chm);
    k_filt<<<1, 64, 0, stream>>>(chm, lisa_w + i*768, filt);
    k_lisa_h<<<Bz*Cc*Tt, 64, 0, stream>>>(buf1, buf2, filt, lisa_in + i*64, lisa_ll + i*64, lisa_lh + i*64, dils[i]);
    k_ln4d<<<2016, 256, 0, stream>>>(buf2, buf1, br_g + (i+3)*64, br_b + (i+3)*64);
    k_chmean<<<256, 256, 0, stream>>>(buf1, chm);
    k_filt<<<1, 64, 0, stream>>>(chm, lisa_w + (i+3)*768, filt);
    k_colmean<<<dim3(3, 64, 4), 256, 0, stream>>>(buf1, gapv);
    k_lisa_v<<<dim3(30, 64, 4), 256, 0, stream>>>(buf1, x, buf0, filt, gapv,
        lisa_in + (i+3)*64, lisa_ll + (i+3)*64, lisa_lh + (i+3)*64,
        mix_g + i*64, mix_b + i*64, dils[i], i > 0 ? 1 : 0);
  }
  k_convb<<<2016, 256, 0, stream>>>(buf0, buf1, convb_w, convb_b);
  k_gnstat<<<dim3(64, 4), 256, 0, stream>>>(buf1, stat);
  k_gnapply<<<32250, 256, 0, stream>>>(buf1, gn_g, gn_b, convb_a, stat);
  k_qkv<<<dim3(1000, 4), 256, 0, stream>>>(buf1,
      q_w, q_b, q_a, q_lg, q_lb,
      k_w, k_b, k_a, k_lg, k_lb,
      v_w, v_b, v_a, v_lg, v_lb,
      Qm, Km, Vm);
  k_vt<<<dim3(16, 33, 16), 256, 0, stream>>>((const ushort*)Vm, Vt);
  // scores: S = (Q @ K^T) / sqrt(516)
  k_gemm<0><<<dim3(8, 8, 16), 256, 0, stream>>>(
      (const ushort*)Qm, KQK, (long)Tt*KQK,
      (const ushort*)Km, KQK, (long)Tt*KQK,
      S, (long)Tt*Tt, Tt, Tt, KQK, 0.04402254531f);
  k_softmax<<<16000, 256, 0, stream>>>(S);
  // PV: out = P @ V  (P bf16 in S region, row stride LDP; Vt is B^T)
  k_gemm<1><<<dim3(17, 8, 16), 256, 0, stream>>>(
      (const ushort*)S, LDP, (long)Tt*LDP,
      Vt, KPV, (long)NV*KPV,
      out, 0, Tt, NV, KPV, 1.f);
  k_proj<<<dim3(1000, 4), 256, 0, stream>>>(out, buf1, p_w, p_b, p_a, p_lg, p_lb);
}

// Round 4
// 3356.978 us; speedup vs baseline: 1.6222x; 1.1051x over previous
//
#include <hip/hip_runtime.h>
#include <hip/hip_bf16.h>

#define Bz 4
#define Cc 64
#define Tt 1000
#define Ff 129
#define TF 129000            // Tt*Ff
#define CTF 8256000          // Cc*TF
#define SZ 33024000L         // Bz*CTF
#define EPSv 1e-5f

#define KQK 544              // 516 padded to mult of 32
#define KPV 1024             // 1000 padded
#define LDP 2000             // P row stride in bf16 (= 1000 f32 reused in place)
#define NV 2064              // 16*129

typedef __attribute__((ext_vector_type(8))) short bf16x8;
typedef __attribute__((ext_vector_type(4))) float f32x4;

// bf16 <-> bits helpers (no .data member on this ROCm's __hip_bfloat16)
__device__ __forceinline__ ushort bf_bits(__hip_bfloat16 h){
  union { __hip_bfloat16 h; ushort u; } c; c.h = h; return c.u;
}
__device__ __forceinline__ float bits_f32(ushort u){
  union { float f; unsigned int i; } c; c.i = ((unsigned int)u) << 16; return c.f;
}

// ---------------- reduction helpers ----------------
__device__ __forceinline__ float wave_sum(float v){
#pragma unroll
  for (int o = 32; o; o >>= 1) v += __shfl_down(v, o, 64);
  return v;
}
__device__ __forceinline__ float wave_bcast_sum(float v){
#pragma unroll
  for (int o = 1; o < 64; o <<= 1) v += __shfl_xor(v, o, 64);
  return v;
}
__device__ __forceinline__ float blk_sum256(float v, float* red){
  __syncthreads();
  v = wave_sum(v);
  int tid = threadIdx.x;
  if ((tid & 63) == 0) red[tid >> 6] = v;
  __syncthreads();
  return red[0] + red[1] + red[2] + red[3];
}
__device__ __forceinline__ float blk_max256(float v, float* red){
  __syncthreads();
#pragma unroll
  for (int o = 32; o; o >>= 1) v = fmaxf(v, __shfl_down(v, o, 64));
  int tid = threadIdx.x;
  if ((tid & 63) == 0) red[tid >> 6] = v;
  __syncthreads();
  return fmaxf(fmaxf(red[0], red[1]), fmaxf(red[2], red[3]));
}

// ---------------- misc ----------------
__global__ void k_zero(float* s){ if (threadIdx.x < 8) s[threadIdx.x] = 0.f; }

// ln4d: LN over channel axis per (b,t,f); std = sqrt(max(var, EPS))
__global__ void k_ln4d(const float* __restrict__ in, float* __restrict__ out,
                       const float* __restrict__ g, const float* __restrict__ be){
  int gid = blockIdx.x*256 + threadIdx.x;
  if (gid >= Bz*TF) return;
  int b = gid / TF, p = gid - b*TF;
  size_t base = (size_t)b*CTF + p;
  float v[64]; float s1 = 0.f, s2 = 0.f;
#pragma unroll
  for (int c = 0; c < 64; c++){ float x = in[base + (size_t)c*TF]; v[c] = x; s1 += x; s2 += x*x; }
  float mu = s1*(1.f/64.f);
  float var = s2*(1.f/64.f) - mu*mu;
  float rstd = rsqrtf(fmaxf(var, EPSv));
#pragma unroll
  for (int c = 0; c < 64; c++) out[base + (size_t)c*TF] = (v[c]-mu)*rstd*g[c] + be[c];
}

// per-(b,c) mean over (t,f)
__global__ void k_chmean(const float* __restrict__ in, float* __restrict__ m){
  int bc = blockIdx.x;
  const float4* p = (const float4*)(in + (size_t)bc*TF);
  float s = 0.f;
  for (int i = threadIdx.x; i < TF/4; i += 256){ float4 u = p[i]; s += u.x+u.y+u.z+u.w; }
  __shared__ float red[4];
  s = blk_sum256(s, red);
  if (threadIdx.x == 0) m[bc] = s * (1.f/(float)TF);
}

__global__ void k_filt(const float* __restrict__ m, const float* __restrict__ w, float* __restrict__ filt){
  int t = threadIdx.x;
  if (t >= Bz*12) return;
  int b = t/12, gk = t - b*12;
  float s = 0.f;
  for (int c = 0; c < 64; c++) s += m[b*64+c]*w[gk*64+c];
  filt[t] = tanhf(s);
}

// lisa horizontal: one wave per (b,c,t) row of 129
__global__ void k_lisa_h(const float* __restrict__ in, float* __restrict__ out,
                         const float* __restrict__ filt, const float* __restrict__ iap,
                         const float* __restrict__ llp, const float* __restrict__ lhp, int dil){
  __shared__ float r[132];
  int row = blockIdx.x;
  int c = (row / Tt) % Cc;
  int b = row / (Tt*Cc);
  size_t base = (size_t)row * Ff;
  int lane = threadIdx.x;
  float s = 0.f;
  for (int f = lane; f < Ff; f += 64){ float x = in[base+f]; r[f] = x; s += x; }
  s = wave_bcast_sum(s);
  float gap = s * (1.f/129.f);
  __syncthreads();
  int g3 = b*12 + (c>>4)*3;
  float w0 = filt[g3], w1 = filt[g3+1], w2 = filt[g3+2];
  float ia = iap[c], ll = llp[c], lh1 = lhp[c] + 1.f, ia1 = ia + 1.f;
  for (int f = lane; f < Ff; f += 64){
    int fm = f - dil; fm = fm < 0 ? -fm : fm;
    int fp = f + dil; fp = fp > 128 ? 256 - fp : fp;
    float conv = w0*r[fm] + w1*r[f] + w2*r[fp];
    out[base+f] = (conv*ia1 - ia*gap)*ll + r[f]*lh1;
  }
}

// column means over t per (b,c,f)
__global__ void k_colmean(const float* __restrict__ in, float* __restrict__ gapv){
  int lane = threadIdx.x & 63, strip = threadIdx.x >> 6;
  int f = blockIdx.x*64 + lane;
  int c = blockIdx.y, b = blockIdx.z;
  size_t cb = ((size_t)(b*Cc + c))*TF + f;
  float s = 0.f;
  if (f < Ff){ for (int t = strip; t < Tt; t += 4) s += in[cb + (size_t)t*Ff]; }
  __shared__ float sm[256];
  sm[threadIdx.x] = s; __syncthreads();
  if (strip == 0 && f < Ff){
    float tot = sm[threadIdx.x] + sm[threadIdx.x+64] + sm[threadIdx.x+128] + sm[threadIdx.x+192];
    gapv[(b*Cc + c)*Ff + f] = tot * (1.f/(float)Tt);
  }
}

// lisa vertical fused with bsum accumulate
__global__ void k_lisa_v(const float* __restrict__ in, const float* __restrict__ x,
                         float* __restrict__ A, const float* __restrict__ filt,
                         const float* __restrict__ gapv,
                         const float* __restrict__ iap, const float* __restrict__ llp,
                         const float* __restrict__ lhp,
                         const float* __restrict__ mgp, const float* __restrict__ mbp,
                         int dil, int accum){
  int lane = threadIdx.x & 63, strip = threadIdx.x >> 6;
  int ftile = blockIdx.x % 3, tch = blockIdx.x / 3;
  int f = ftile*64 + lane;
  if (f >= Ff) return;
  int c = blockIdx.y, b = blockIdx.z;
  int g3 = b*12 + (c>>4)*3;
  float w0 = filt[g3], w1 = filt[g3+1], w2 = filt[g3+2];
  float ia = iap[c], ll = llp[c], lh1 = lhp[c]+1.f, ia1 = ia+1.f;
  float mg = mgp[c], mb = mbp[c];
  float gap = gapv[(b*Cc+c)*Ff + f];
  size_t cb = ((size_t)(b*Cc + c))*TF + f;
  int tend = tch*100 + 100;
  for (int t = tch*100 + strip; t < tend; t += 4){
    int tm = t - dil; tm = tm < 0 ? -tm : tm;
    int tp = t + dil; tp = tp > 999 ? 1998 - tp : tp;
    float vm = in[cb + (size_t)tm*Ff];
    float vc = in[cb + (size_t)t*Ff];
    float vp = in[cb + (size_t)tp*Ff];
    float conv = w0*vm + w1*vc + w2*vp;
    float val = (conv*ia1 - ia*gap)*ll + vc*lh1;
    float o = mg*val + mb*x[cb + (size_t)t*Ff];
    size_t oi = cb + (size_t)t*Ff;
    A[oi] = accum ? (A[oi] + o) : o;
  }
}

// 1x1 conv 64->64
__global__ void k_convb(const float* __restrict__ in, float* __restrict__ out,
                        const float* __restrict__ W, const float* __restrict__ bias){
  __shared__ float Ws[4096];
  for (int i = threadIdx.x; i < 4096; i += 256) Ws[i] = W[i];
  __syncthreads();
  int gid = blockIdx.x*256 + threadIdx.x;
  if (gid >= Bz*TF) return;
  int b = gid / TF, p = gid - b*TF;
  size_t base = (size_t)b*CTF + p;
  float v[64];
#pragma unroll
  for (int c = 0; c < 64; c++) v[c] = in[base + (size_t)c*TF];
  for (int o = 0; o < 64; o++){
    float s = bias[o];
    const float4* w4 = (const float4*)&Ws[o*64];
#pragma unroll
    for (int c = 0; c < 16; c++){
      float4 w = w4[c];
      s += v[4*c]*w.x + v[4*c+1]*w.y + v[4*c+2]*w.z + v[4*c+3]*w.w;
    }
    out[base + (size_t)o*TF] = s;
  }
}

// per-batch global stats
__global__ void k_gnstat(const float* __restrict__ y, float* __restrict__ stat){
  int b = blockIdx.y;
  const float4* p = (const float4*)(y + (size_t)b*CTF + (size_t)blockIdx.x*TF);
  float s1 = 0.f, s2 = 0.f;
  for (int i = threadIdx.x; i < TF/4; i += 256){
    float4 u = p[i];
    s1 += u.x+u.y+u.z+u.w;
    s2 += u.x*u.x+u.y*u.y+u.z*u.z+u.w*u.w;
  }
  __shared__ float red[4];
  s1 = blk_sum256(s1, red);
  s2 = blk_sum256(s2, red);
  if (threadIdx.x == 0){ atomicAdd(&stat[b*2], s1); atomicAdd(&stat[b*2+1], s2); }
}

__global__ void k_gnapply(float* __restrict__ y, const float* __restrict__ g,
                          const float* __restrict__ be, const float* __restrict__ a,
                          const float* __restrict__ stat){
  size_t gid = (size_t)blockIdx.x*256 + threadIdx.x;
  if (gid >= (size_t)(SZ/4)) return;
  size_t e0 = gid*4;
  int b = (int)(e0 / CTF);
  int c = (int)((e0 / TF) & 63);
  float mu = stat[b*2] * (1.f/(float)CTF);
  float var = stat[b*2+1] * (1.f/(float)CTF) - mu*mu;
  float rstd = rsqrtf(var + EPSv);
  float gc = g[c], bc = be[c], al = a[0];
  float4 v = *(const float4*)(y + e0);
  float o[4] = {v.x, v.y, v.z, v.w};
#pragma unroll
  for (int i = 0; i < 4; i++){
    float z = (o[i]-mu)*rstd*gc + bc;
    o[i] = z >= 0.f ? z : al*z;
  }
  *(float4*)(y + e0) = make_float4(o[0], o[1], o[2], o[3]);
}

// ---------------- QKV projection, stage P: Z[b][r=0..95][p] = prelu(W y + b), bf16 ----
// rows 0-15: Q(h*4+e), 16-31: K, 32-95: V(h*16+d)
__global__ __launch_bounds__(256) void k_qkvP(const float* __restrict__ Y,
    const float* __restrict__ qw, const float* __restrict__ qb, const float* __restrict__ qa,
    const float* __restrict__ kw, const float* __restrict__ kb, const float* __restrict__ ka,
    const float* __restrict__ vw, const float* __restrict__ vb, const float* __restrict__ va,
    __hip_bfloat16* __restrict__ Z){
  __shared__ float Ws[96*64];
  __shared__ float Bs[96], As[96];
  for (int i = threadIdx.x; i < 96*64; i += 256){
    int r = i >> 6, c = i & 63;
    float w;
    if (r < 16) w = qw[(r)*64 + c];
    else if (r < 32) w = kw[(r-16)*64 + c];
    else w = vw[(r-32)*64 + c];
    Ws[i] = w;
  }
  if (threadIdx.x < 96){
    int r = threadIdx.x;
    if (r < 16){ Bs[r] = qb[r]; As[r] = qa[r>>2]; }
    else if (r < 32){ Bs[r] = kb[r-16]; As[r] = ka[(r-16)>>2]; }
    else { Bs[r] = vb[r-32]; As[r] = va[(r-32)>>4]; }
  }
  __syncthreads();
  int gid = blockIdx.x*256 + threadIdx.x;
  if (gid >= Bz*TF) return;
  int b = gid / TF, p = gid - b*TF;
  size_t base = (size_t)b*CTF + p;
  float v[64];
#pragma unroll
  for (int c = 0; c < 64; c++) v[c] = Y[base + (size_t)c*TF];
  __hip_bfloat16* zb = Z + ((size_t)b*96)*TF + p;
  for (int r = 0; r < 96; r++){
    float s = Bs[r];
    const float4* w4 = (const float4*)&Ws[r*64];
#pragma unroll
    for (int c = 0; c < 16; c++){
      float4 w = w4[c];
      s += v[4*c]*w.x + v[4*c+1]*w.y + v[4*c+2]*w.z + v[4*c+3]*w.w;
    }
    s = s >= 0.f ? s : As[r]*s;
    zb[(size_t)r*TF] = __float2bfloat16(s);
  }
}

// ---------------- QKV stage N: per-(b,t) LN over (e,f) per (h,kind), write Qm/Km/Vm ----
__global__ __launch_bounds__(256) void k_qkvN(const __hip_bfloat16* __restrict__ Z,
    const float* __restrict__ qg, const float* __restrict__ qz,
    const float* __restrict__ kg, const float* __restrict__ kz,
    const float* __restrict__ vg, const float* __restrict__ vz,
    __hip_bfloat16* __restrict__ Qm, __hip_bfloat16* __restrict__ Km,
    __hip_bfloat16* __restrict__ Vm){
  __shared__ ushort zt[96*129];
  __shared__ float ps1[256], ps2[256];
  __shared__ float mug[12], rsg[12];
  int t = blockIdx.x, b = blockIdx.y;
  const ushort* Zb = (const ushort*)(Z + ((size_t)b*96)*TF + (size_t)t*Ff);
  int tid = threadIdx.x;
  // unit decomposition: 24 units of 516 items; 10 threads per unit (240 active)
  int u = tid/10, l = tid - u*10;
  int kind = 0, h = 0, jbase = 0, g = 0, rbase = 0;
  bool act = tid < 240;
  if (act){
    if (u < 4){ kind = 0; h = u; jbase = 0; g = h; rbase = h*4; }
    else if (u < 8){ kind = 1; h = u-4; jbase = 0; g = 4+h; rbase = 16+h*4; }
    else { int uv = u-8; kind = 2; h = uv>>2; jbase = (uv&3)*516; g = 8+h; rbase = 32+h*16; }
  }
  float s1 = 0.f, s2 = 0.f;
  if (act){
    for (int j = jbase + l; j < jbase + 516; j += 10){
      int e = j/129, f = j - e*129;
      int r = rbase + e;
      ushort raw = Zb[(size_t)r*TF + f];
      float z = bits_f32(raw);
      s1 += z; s2 += z*z;
      zt[r*129 + f] = raw;
    }
  }
  ps1[tid] = s1; ps2[tid] = s2;
  __syncthreads();
  if (tid < 12){
    int t0, cnt; float n;
    if (tid < 8){ t0 = tid*10; cnt = 10; n = 516.f; }
    else { t0 = (8 + (tid-8)*4)*10; cnt = 40; n = 2064.f; }
    float a = 0.f, q = 0.f;
    for (int i = 0; i < cnt; i++){ a += ps1[t0+i]; q += ps2[t0+i]; }
    float mu = a/n;
    mug[tid] = mu;
    rsg[tid] = rsqrtf(q/n - mu*mu + EPSv);
  }
  __syncthreads();
  if (act){
    float mu = mug[g], rs = rsg[g];
    size_t obase = (size_t)(h*Bz + b)*Tt + t;
    const float* lg; const float* lb; __hip_bfloat16* outp;
    if (kind == 0){ lg = qg + h*516; lb = qz + h*516; outp = Qm + obase*KQK; }
    else if (kind == 1){ lg = kg + h*516; lb = kz + h*516; outp = Km + obase*KQK; }
    else { lg = vg + h*2064; lb = vz + h*2064; outp = Vm + obase*NV; }
    for (int j = jbase + l; j < jbase + 516; j += 10){
      int e = j/129, f = j - e*129;
      int r = rbase + e;
      float z = bits_f32(zt[r*129 + f]);
      float val = (z - mu)*rs*lg[j] + lb[j];
      outp[j] = __float2bfloat16(val);
    }
  } else {
    // pad K-dim 516->544 with zeros for Q and K rows (224 pads, 14 per thread)
    int i0 = (tid - 240)*14;
    for (int i = i0; i < i0 + 14; i++){
      int kk = i/112, pj = i - kk*112;
      int hh = pj/28, off = 516 + (pj - hh*28);
      size_t obase = (size_t)(hh*Bz + b)*Tt + t;
      (kk ? Km : Qm)[obase*KQK + off] = __float2bfloat16(0.f);
    }
  }
}

// transpose V: Vm[hb][t][n] -> Vt[hb][n][tp] with tp-stride KPV, zero pad t>=1000
__global__ void k_vt(const ushort* __restrict__ Vm, ushort* __restrict__ Vt){
  __shared__ ushort tile[64][72];
  int t0 = blockIdx.x*64, n0 = blockIdx.y*64, hb = blockIdx.z;
  const ushort* src = Vm + (size_t)hb*Tt*NV;
  ushort* dst = Vt + (size_t)hb*NV*KPV;
  int nl = threadIdx.x & 63, tl = threadIdx.x >> 6;
#pragma unroll
  for (int i = 0; i < 16; i++){
    int t = tl + i*4;
    int gt = t0 + t, gn = n0 + nl;
    ushort v = 0;
    if (gt < Tt && gn < NV) v = src[(size_t)gt*NV + gn];
    tile[t][nl] = v;
  }
  __syncthreads();
  int tl2 = threadIdx.x & 63, nl2 = threadIdx.x >> 6;
#pragma unroll
  for (int i = 0; i < 16; i++){
    int n = nl2 + i*4;
    int gn = n0 + n;
    if (gn < NV) dst[(size_t)gn*KPV + t0 + tl2] = tile[tl2][n];
  }
}

// ---------------- bf16 MFMA GEMM: C[M,N] = A[M,Kc] * B^T[N,Kc]  ----------------
template<int MODE>
__global__ __launch_bounds__(256) void k_gemm(
    const ushort* __restrict__ A, int lda, long strideA,
    const ushort* __restrict__ Bt, int ldb, long strideB,
    float* __restrict__ C, long strideC,
    int M, int N, int Kc, float alpha){
  __shared__ ushort As[128*40];
  __shared__ ushort Bs[128*40];
  int hb = blockIdx.z;
  const ushort* Ab = A + (long)hb*strideA;
  const ushort* Bb = Bt + (long)hb*strideB;
  int i0 = blockIdx.y*128, j0 = blockIdx.x*128;
  int tid = threadIdx.x;
  int wave = tid >> 6, lane = tid & 63;
  int wm = (wave >> 1)*64, wn = (wave & 1)*64;
  int col16 = lane & 15, quad = lane >> 4;
  f32x4 acc[4][4] = {};
  int srow = tid >> 2;
  int scol = (tid & 3)*8;
  for (int k0 = 0; k0 < Kc; k0 += 32){
#pragma unroll
    for (int r = 0; r < 2; r++){
      int row = srow + r*64;
      int gi = i0 + row;
      float4 va = (gi < M) ? *(const float4*)(Ab + (long)gi*lda + k0 + scol)
                           : make_float4(0.f,0.f,0.f,0.f);
      *(float4*)&As[row*40 + scol] = va;
      int gj = j0 + row;
      float4 vb = (gj < N) ? *(const float4*)(Bb + (long)gj*ldb + k0 + scol)
                           : make_float4(0.f,0.f,0.f,0.f);
      *(float4*)&Bs[row*40 + scol] = vb;
    }
    __syncthreads();
    bf16x8 af[4], bfr[4];
#pragma unroll
    for (int mt = 0; mt < 4; mt++) af[mt]  = *(const bf16x8*)&As[(wm + mt*16 + col16)*40 + quad*8];
#pragma unroll
    for (int nt = 0; nt < 4; nt++) bfr[nt] = *(const bf16x8*)&Bs[(wn + nt*16 + col16)*40 + quad*8];
#pragma unroll
    for (int mt = 0; mt < 4; mt++)
#pragma unroll
      for (int nt = 0; nt < 4; nt++)
        acc[mt][nt] = __builtin_amdgcn_mfma_f32_16x16x32_bf16(af[mt], bfr[nt], acc[mt][nt], 0, 0, 0);
    __syncthreads();
  }
  if (MODE == 0){
    float* Cb = C + (long)hb*strideC;
#pragma unroll
    for (int mt = 0; mt < 4; mt++){
      int ibase = i0 + wm + mt*16 + quad*4;
#pragma unroll
      for (int nt = 0; nt < 4; nt++){
        int j = j0 + wn + nt*16 + col16;
        if (j < N){
#pragma unroll
          for (int rg = 0; rg < 4; rg++){
            int i = ibase + rg;
            if (i < M) Cb[(long)i*N + j] = acc[mt][nt][rg]*alpha;
          }
        }
      }
    }
  } else {
    int h = hb >> 2, b = hb & 3;
#pragma unroll
    for (int mt = 0; mt < 4; mt++){
      int ibase = i0 + wm + mt*16 + quad*4;
#pragma unroll
      for (int nt = 0; nt < 4; nt++){
        int n = j0 + wn + nt*16 + col16;
        if (n < NV){
          int d = n / 129, f = n - d*129;
          float* oc = C + ((long)(b*64 + h*16 + d)*Tt)*Ff + f;
#pragma unroll
          for (int rg = 0; rg < 4; rg++){
            int i = ibase + rg;
            if (i < M) oc[(long)i*Ff] = acc[mt][nt][rg];
          }
        }
      }
    }
  }
}

// softmax over row of 1000 f32; writes P bf16 (padded to 1024, zeros) in place
__global__ void k_softmax(float* __restrict__ S){
  float* row = S + (size_t)blockIdx.x * Tt;
  __hip_bfloat16* prow = (__hip_bfloat16*)row;
  int tid = threadIdx.x;
  __shared__ float red[4];
  float lv[4];
#pragma unroll
  for (int k = 0; k < 4; k++){ int idx = tid + k*256; lv[k] = (idx < Tt) ? row[idx] : -1e30f; }
  float m = fmaxf(fmaxf(lv[0], lv[1]), fmaxf(lv[2], lv[3]));
  m = blk_max256(m, red);
  float s = 0.f;
#pragma unroll
  for (int k = 0; k < 4; k++){ lv[k] = __expf(lv[k]-m); s += lv[k]; }
  s = blk_sum256(s, red);
  float inv = 1.f/s;
#pragma unroll
  for (int k = 0; k < 4; k++){
    int idx = tid + k*256;
    prow[idx] = __float2bfloat16(idx < Tt ? lv[k]*inv : 0.f);
  }
}

// proj 1x1 conv + scalar prelu + LN over (C,F) per (b,t) + residual; in-place on d_out
__global__ void k_proj(float* __restrict__ Out, const float* __restrict__ Y,
                       const float* __restrict__ W, const float* __restrict__ bias,
                       const float* __restrict__ pa, const float* __restrict__ lng,
                       const float* __restrict__ lnb){
  __shared__ float ot[64][130];
  __shared__ float Ws[4096];
  __shared__ float red[4];
  int t = blockIdx.x, b = blockIdx.y;
  size_t base = (size_t)b*CTF + (size_t)t*Ff;
  for (int i = threadIdx.x; i < 4096; i += 256) Ws[i] = W[i];
  for (int idx = threadIdx.x; idx < 64*Ff; idx += 256){
    int c = idx / Ff, f = idx - c*Ff;
    ot[c][f] = Out[base + (size_t)c*TF + f];
  }
  __syncthreads();
  float alpha = pa[0];
  float pva[17], pvb[17];
  float s1 = 0.f, s2 = 0.f;
#pragma unroll
  for (int ki = 0; ki < 17; ki++){
    int idx = threadIdx.x + ki*256;
    if (idx < 32*Ff){
      int o2 = idx / Ff, f = idx - o2*Ff;
      int o = o2*2;
      const float* wa = &Ws[o*64]; const float* wb = wa + 64;
      float sa = bias[o], sb = bias[o+1];
#pragma unroll 8
      for (int c = 0; c < 64; c++){ float v = ot[c][f]; sa += v*wa[c]; sb += v*wb[c]; }
      sa = sa >= 0.f ? sa : alpha*sa;
      sb = sb >= 0.f ? sb : alpha*sb;
      pva[ki] = sa; pvb[ki] = sb;
      s1 += sa + sb; s2 += sa*sa + sb*sb;
    }
  }
  s1 = blk_sum256(s1, red);
  s2 = blk_sum256(s2, red);
  const float n = 64.f*129.f;
  float mu = s1/n;
  float rstd = rsqrtf(s2/n - mu*mu + EPSv);
#pragma unroll
  for (int ki = 0; ki < 17; ki++){
    int idx = threadIdx.x + ki*256;
    if (idx < 32*Ff){
      int o2 = idx / Ff, f = idx - o2*Ff;
      int o = o2*2;
      float va = (pva[ki]-mu)*rstd*lng[o*Ff+f] + lnb[o*Ff+f];
      float vb = (pvb[ki]-mu)*rstd*lng[(o+1)*Ff+f] + lnb[(o+1)*Ff+f];
      Out[base + (size_t)o*TF + f]     = va + Y[base + (size_t)o*TF + f];
      Out[base + (size_t)(o+1)*TF + f] = vb + Y[base + (size_t)(o+1)*TF + f];
    }
  }
}

extern "C" void kernel_launch(void* const* d_in, const int* in_sizes, int n_in,
                              void* d_out, int out_size, void* d_ws, size_t ws_size,
                              hipStream_t stream){
  const float* x       = (const float*)d_in[0];
  const float* br_g    = (const float*)d_in[1];
  const float* br_b    = (const float*)d_in[2];
  const float* lisa_w  = (const float*)d_in[3];
  const float* lisa_in = (const float*)d_in[4];
  const float* lisa_ll = (const float*)d_in[5];
  const float* lisa_lh = (const float*)d_in[6];
  const float* mix_g   = (const float*)d_in[7];
  const float* mix_b   = (const float*)d_in[8];
  const float* convb_w = (const float*)d_in[9];
  const float* convb_b = (const float*)d_in[10];
  const float* gn_g    = (const float*)d_in[11];
  const float* gn_b    = (const float*)d_in[12];
  const float* convb_a = (const float*)d_in[13];
  const float* q_w  = (const float*)d_in[14];
  const float* q_b  = (const float*)d_in[15];
  const float* q_a  = (const float*)d_in[16];
  const float* q_lg = (const float*)d_in[17];
  const float* q_lb = (const float*)d_in[18];
  const float* k_w  = (const float*)d_in[19];
  const float* k_b  = (const float*)d_in[20];
  const float* k_a  = (const float*)d_in[21];
  const float* k_lg = (const float*)d_in[22];
  const float* k_lb = (const float*)d_in[23];
  const float* v_w  = (const float*)d_in[24];
  const float* v_b  = (const float*)d_in[25];
  const float* v_a  = (const float*)d_in[26];
  const float* v_lg = (const float*)d_in[27];
  const float* v_lb = (const float*)d_in[28];
  const float* p_w  = (const float*)d_in[29];
  const float* p_b  = (const float*)d_in[30];
  const float* p_a  = (const float*)d_in[31];
  const float* p_lg = (const float*)d_in[32];
  const float* p_lb = (const float*)d_in[33];

  float* out  = (float*)d_out;
  float* buf0 = (float*)d_ws;          // bsum -> Z -> Vt|S
  float* buf1 = buf0 + SZ;             // ln temp -> Y ("output")
  float* buf2 = buf1 + SZ;             // lisa_h temp -> Qm|Km|Vm (bf16)
  float* chm  = buf2 + SZ;             // 256
  float* filt = chm + 256;             // 48 (pad 64)
  float* stat = filt + 64;             // 8  (pad 16)
  float* gapv = stat + 16;             // 33024

  if (ws_size < (3*(size_t)SZ + 40000)*sizeof(float)) return;

  __hip_bfloat16* Qm = (__hip_bfloat16*)buf2;                 // 16*1000*544
  __hip_bfloat16* Km = Qm + (size_t)16*Tt*KQK;                // 16*1000*544
  __hip_bfloat16* Vm = Km + (size_t)16*Tt*KQK;                // 16*1000*2064
  __hip_bfloat16* Z  = (__hip_bfloat16*)buf0;                 // 4*96*129000 bf16 (99 MB)
  ushort* Vt = (ushort*)buf0;                                 // 16*2064*1024 bf16 (after Z dead)
  float*  S  = buf0 + (size_t)16*NV*KPV/2;                    // 16*1000*1000 f32

  k_zero<<<1, 64, 0, stream>>>(stat);

  const int dils[3] = {3, 5, 7};
  for (int i = 0; i < 3; i++){
    k_ln4d<<<2016, 256, 0, stream>>>(x, buf1, br_g + i*64, br_b + i*64);
    k_chmean<<<256, 256, 0, stream>>>(buf1, chm);
    k_filt<<<1, 64, 0, stream>>>(chm, lisa_w + i*768, filt);
    k_lisa_h<<<Bz*Cc*Tt, 64, 0, stream>>>(buf1, buf2, filt, lisa_in + i*64, lisa_ll + i*64, lisa_lh + i*64, dils[i]);
    k_ln4d<<<2016, 256, 0, stream>>>(buf2, buf1, br_g + (i+3)*64, br_b + (i+3)*64);
    k_chmean<<<256, 256, 0, stream>>>(buf1, chm);
    k_filt<<<1, 64, 0, stream>>>(chm, lisa_w + (i+3)*768, filt);
    k_colmean<<<dim3(3, 64, 4), 256, 0, stream>>>(buf1, gapv);
    k_lisa_v<<<dim3(30, 64, 4), 256, 0, stream>>>(buf1, x, buf0, filt, gapv,
        lisa_in + (i+3)*64, lisa_ll + (i+3)*64, lisa_lh + (i+3)*64,
        mix_g + i*64, mix_b + i*64, dils[i], i > 0 ? 1 : 0);
  }
  k_convb<<<2016, 256, 0, stream>>>(buf0, buf1, convb_w, convb_b);
  k_gnstat<<<dim3(64, 4), 256, 0, stream>>>(buf1, stat);
  k_gnapply<<<32250, 256, 0, stream>>>(buf1, gn_g, gn_b, convb_a, stat);
  k_qkvP<<<2016, 256, 0, stream>>>(buf1, q_w, q_b, q_a, k_w, k_b, k_a, v_w, v_b, v_a, Z);
  k_qkvN<<<dim3(1000, 4), 256, 0, stream>>>(Z, q_lg, q_lb, k_lg, k_lb, v_lg, v_lb, Qm, Km, Vm);
  k_vt<<<dim3(16, 33, 16), 256, 0, stream>>>((const ushort*)Vm, Vt);
  k_gemm<0><<<dim3(8, 8, 16), 256, 0, stream>>>(
      (const ushort*)Qm, KQK, (long)Tt*KQK,
      (const ushort*)Km, KQK, (long)Tt*KQK,
      S, (long)Tt*Tt, Tt, Tt, KQK, 0.04402254531f);
  k_softmax<<<16000, 256, 0, stream>>>(S);
  k_gemm<1><<<dim3(17, 8, 16), 256, 0, stream>>>(
      (const ushort*)S, LDP, (long)Tt*LDP,
      Vt, KPV, (long)NV*KPV,
      out, 0, Tt, NV, KPV, 1.f);
  k_proj<<<dim3(1000, 4), 256, 0, stream>>>(out, buf1, p_w, p_b, p_a, p_lg, p_lb);
}